// Round 8
// baseline (625.579 us; speedup 1.0000x reference)
//
#include <hip/hip_runtime.h>
#include <math.h>

#define NB 16      // batch
#define LAT 128
#define HID 256
#define NN 256     // nodes
#define NH 4       // heads
#define JT 4       // dst-tile per gat block

__device__ __forceinline__ float lrelu02(float x){ return x > 0.f ? x : 0.2f*x; }
__device__ __forceinline__ float eluf(float x){ return x > 0.f ? x : expm1f(x); }

// ---------------- K1: h2 = relu(relu(x@W0+b0)@W1+b1)  [16,256] ----------------
__global__ __launch_bounds__(256) void k_mlp12(const float* __restrict__ x,
    const float* __restrict__ W0, const float* __restrict__ b0,
    const float* __restrict__ W1, const float* __restrict__ b1,
    float* __restrict__ h2)
{
    __shared__ float xs[LAT];
    __shared__ float h1s[HID];
    int b = blockIdx.x, t = threadIdx.x;
    if (t < LAT) xs[t] = x[b*LAT + t];
    __syncthreads();
    float acc = b0[t];
    for (int k = 0; k < LAT; ++k) acc = fmaf(xs[k], W0[k*HID + t], acc);
    h1s[t] = fmaxf(acc, 0.f);
    __syncthreads();
    float acc2 = b1[t];
    for (int k = 0; k < HID; ++k) acc2 = fmaf(h1s[k], W1[k*HID + t], acc2);
    h2[b*HID + t] = fmaxf(acc2, 0.f);
}

// ---------------- K2: h3 = h2 @ W2 + b2, float4-wide streaming -----------------
// Grid 512 x 256 thr. Thread = (kh = t>>5 in 0..7, c = t&31): 4 cols (float4),
// 32 k's. ABAB 8-deep float4 prefetch (128B in flight, all indices static).
// kh pairs share a wave (lanes 0-31 / 32-63) -> h2T reads 2-addr (free),
// reduce via shfl_xor(32); cross-wave via conflict-free red4[w][b][c].
#define FMA_B(HB, ACC) \
    ACC.x = fmaf((HB), wv.x, ACC.x); ACC.y = fmaf((HB), wv.y, ACC.y); \
    ACC.z = fmaf((HB), wv.z, ACC.z); ACC.w = fmaf((HB), wv.w, ACC.w);

#define KSTEP(KOFF, WVV) { \
    float4 wv = (WVV); \
    int kk = khb + (KOFF); \
    const float4* hq = (const float4*)&h2f[kk*20]; \
    float4 q0 = hq[0], q1 = hq[1], q2 = hq[2], q3 = hq[3]; \
    FMA_B(q0.x, acc[0])  FMA_B(q0.y, acc[1]) \
    FMA_B(q0.z, acc[2])  FMA_B(q0.w, acc[3]) \
    FMA_B(q1.x, acc[4])  FMA_B(q1.y, acc[5]) \
    FMA_B(q1.z, acc[6])  FMA_B(q1.w, acc[7]) \
    FMA_B(q2.x, acc[8])  FMA_B(q2.y, acc[9]) \
    FMA_B(q2.z, acc[10]) FMA_B(q2.w, acc[11]) \
    FMA_B(q3.x, acc[12]) FMA_B(q3.y, acc[13]) \
    FMA_B(q3.z, acc[14]) FMA_B(q3.w, acc[15]) }

__global__ __launch_bounds__(256, 3) void k_h3w(
    const float* __restrict__ h2, const float* __restrict__ W2,
    const float* __restrict__ b2, float* __restrict__ h3)
{
    __shared__ float  h2f[HID*20];        // [k][b] stride 20, 20KB
    __shared__ float4 red4[4][16][32];    // [w][b][c] 32KB, conflict-free
    int t = threadIdx.x;
    int l = t & 63, w = t >> 6;
    int kh = t >> 5, c = t & 31;
    size_t col0 = (size_t)blockIdx.x * 128;
    for (int idx = t; idx < NB*HID; idx += 256) {
        int b = idx >> 8, k = idx & 255;
        h2f[k*20 + b] = h2[idx];
    }
    __syncthreads();
    float4 acc[16];
    #pragma unroll
    for (int b = 0; b < 16; ++b) acc[b] = make_float4(0.f,0.f,0.f,0.f);
    int khb = kh * 32;
    const float* p = W2 + (size_t)khb*65536 + col0 + c*4;
    float4 wa[8], wb[8];
    #pragma unroll
    for (int u = 0; u < 8; ++u) wa[u] = *(const float4*)(p + (size_t)u*65536);
    #pragma unroll
    for (int u = 0; u < 8; ++u) wb[u] = *(const float4*)(p + (size_t)(8+u)*65536);
    #pragma unroll
    for (int u = 0; u < 8; ++u) { KSTEP(u, wa[u]); wa[u] = *(const float4*)(p + (size_t)(16+u)*65536); }
    #pragma unroll
    for (int u = 0; u < 8; ++u) { KSTEP(8+u, wb[u]); wb[u] = *(const float4*)(p + (size_t)(24+u)*65536); }
    #pragma unroll
    for (int u = 0; u < 8; ++u) { KSTEP(16+u, wa[u]); }
    #pragma unroll
    for (int u = 0; u < 8; ++u) { KSTEP(24+u, wb[u]); }
    // in-wave kh-pair reduce (lanes l and l^32 hold kh 2w / 2w+1)
    #pragma unroll
    for (int b = 0; b < 16; ++b) {
        acc[b].x += __shfl_xor(acc[b].x, 32);
        acc[b].y += __shfl_xor(acc[b].y, 32);
        acc[b].z += __shfl_xor(acc[b].z, 32);
        acc[b].w += __shfl_xor(acc[b].w, 32);
    }
    if (l < 32) {
        #pragma unroll
        for (int b = 0; b < 16; ++b) red4[w][b][l] = acc[b];
    }
    __syncthreads();
    // 512 float4 outputs: o = rep*256+t -> b = o>>5, cq = o&31 (coalesced)
    #pragma unroll
    for (int rep = 0; rep < 2; ++rep) {
        int o = rep*256 + t;
        int b = o >> 5, cq = o & 31;
        float4 v0 = red4[0][b][cq], v1 = red4[1][b][cq];
        float4 v2 = red4[2][b][cq], v3 = red4[3][b][cq];
        float4 bq = *(const float4*)&b2[col0 + cq*4];
        float4 v;
        v.x = v0.x+v1.x+v2.x+v3.x+bq.x;
        v.y = v0.y+v1.y+v2.y+v3.y+bq.y;
        v.z = v0.z+v1.z+v2.z+v3.z+bq.z;
        v.w = v0.w+v1.w+v2.w+v3.w+bq.w;
        *(float4*)&h3[(size_t)b*65536 + col0 + cq*4] = v;
    }
}

// ---------------- K3: in-place gfeat = h3[b,n,:] @ Wg ; a_s/a_d ----------------
// Block = node (grid 256). Wave w -> batches 4w..4w+3; lane l -> cols l*4..+3.
// Wg float4 loads (1KB/wave-instr, L2-hot), ABAB 8-deep static prefetch.
#define GSTEP(K, WVV) { \
    float4 wv = (WVV); \
    float4 hb = *(const float4*)&h3sT[(K)*20 + w*4]; \
    acc[0].x = fmaf(hb.x, wv.x, acc[0].x); acc[0].y = fmaf(hb.x, wv.y, acc[0].y); \
    acc[0].z = fmaf(hb.x, wv.z, acc[0].z); acc[0].w = fmaf(hb.x, wv.w, acc[0].w); \
    acc[1].x = fmaf(hb.y, wv.x, acc[1].x); acc[1].y = fmaf(hb.y, wv.y, acc[1].y); \
    acc[1].z = fmaf(hb.y, wv.z, acc[1].z); acc[1].w = fmaf(hb.y, wv.w, acc[1].w); \
    acc[2].x = fmaf(hb.z, wv.x, acc[2].x); acc[2].y = fmaf(hb.z, wv.y, acc[2].y); \
    acc[2].z = fmaf(hb.z, wv.z, acc[2].z); acc[2].w = fmaf(hb.z, wv.w, acc[2].w); \
    acc[3].x = fmaf(hb.w, wv.x, acc[3].x); acc[3].y = fmaf(hb.w, wv.y, acc[3].y); \
    acc[3].z = fmaf(hb.w, wv.z, acc[3].z); acc[3].w = fmaf(hb.w, wv.w, acc[3].w); }

__global__ __launch_bounds__(256) void k_gfeat(
    float* __restrict__ g, const float* __restrict__ Wg,
    const float* __restrict__ att_src, const float* __restrict__ att_dst,
    float* __restrict__ a_s, float* __restrict__ a_d)
{
    __shared__ float h3sT[HID*20];      // [k][b] stride 20, 20KB
    int t = threadIdx.x;
    int n = blockIdx.x;
    int l = t & 63, w = t >> 6;
    for (int idx = t; idx < NB*HID; idx += 256) {
        int b = idx >> 8, k = idx & 255;
        h3sT[k*20 + b] = g[(size_t)b*65536 + n*HID + k];
    }
    __syncthreads();
    float4 acc[4];
    #pragma unroll
    for (int rr = 0; rr < 4; ++rr) acc[rr] = make_float4(0.f,0.f,0.f,0.f);
    const float* wp = Wg + l*4;
    float4 wa[8], wb[8];
    #pragma unroll
    for (int u = 0; u < 8; ++u) wa[u] = *(const float4*)(wp + u*HID);
    #pragma unroll
    for (int u = 0; u < 8; ++u) wb[u] = *(const float4*)(wp + (8+u)*HID);
    #pragma unroll
    for (int k0 = 0; k0 < HID; k0 += 16) {
        #pragma unroll
        for (int u = 0; u < 8; ++u) {
            GSTEP(k0+u, wa[u]);
            if (k0 + 16 < HID) wa[u] = *(const float4*)(wp + (k0+16+u)*HID);
        }
        #pragma unroll
        for (int u = 0; u < 8; ++u) {
            GSTEP(k0+8+u, wb[u]);
            if (k0 + 24 < HID) wb[u] = *(const float4*)(wp + (k0+24+u)*HID);
        }
    }
    float4 s4 = *(const float4*)&att_src[l*4];
    float4 d4 = *(const float4*)&att_dst[l*4];
    int h = l >> 4;
    #pragma unroll
    for (int rr = 0; rr < 4; ++rr) {
        int b = w*4 + rr;
        *(float4*)&g[(size_t)b*65536 + n*HID + l*4] = acc[rr];
        float ps = acc[rr].x*s4.x + acc[rr].y*s4.y + acc[rr].z*s4.z + acc[rr].w*s4.w;
        float pd = acc[rr].x*d4.x + acc[rr].y*d4.y + acc[rr].z*d4.z + acc[rr].w*d4.w;
        #pragma unroll
        for (int off = 1; off < 16; off <<= 1) {
            ps += __shfl_xor(ps, off);
            pd += __shfl_xor(pd, off);
        }
        if ((l & 15) == 0) {
            a_s[b*(NN*NH) + n*NH + h] = ps;
            a_d[b*(NN*NH) + n*NH + h] = pd;
        }
    }
}

// ---------------- K4: per (b,h,j): S_j = exp(-m_j)/den_j -----------------------
__global__ __launch_bounds__(256) void k_prefden(const float* __restrict__ a_s,
    const float* __restrict__ a_d, float* __restrict__ sArr)
{
    __shared__ float as_sh[NN];
    int id = blockIdx.x;
    int b = id >> 4, h = (id >> 2) & 3, jc = id & 3;
    int t = threadIdx.x;
    as_sh[t] = a_s[b*(NN*NH) + t*NH + h];
    __syncthreads();
    int jl = t >> 2, r = t & 3;
    int j = jc*64 + jl;
    float ad = a_d[b*(NN*NH) + j*NH + h];
    float lm = -INFINITY;
    for (int i = r; i <= j; i += 4) lm = fmaxf(lm, as_sh[i]);
    lm = fmaxf(lm, __shfl_xor(lm, 1));
    lm = fmaxf(lm, __shfl_xor(lm, 2));
    float m = lrelu02(lm + ad);
    float s = 0.f;
    for (int i = r; i <= j; i += 4) s += expf(lrelu02(as_sh[i] + ad) - m);
    s += __shfl_xor(s, 1);
    s += __shfl_xor(s, 2);
    if (r == 0) {
        sArr[b*(NN*NH) + j*NH + h] = expf(-m) / s;
    }
}

// ---------------- K5: fused alpha + aggregate + elu + logits + argmax ----------
__global__ __launch_bounds__(256) void k_gatlog(
    const float* __restrict__ gfeat, const float* __restrict__ a_s,
    const float* __restrict__ a_d, const float* __restrict__ sArr,
    const float* __restrict__ bg, const float* __restrict__ Wl,
    const float* __restrict__ bl, const float* __restrict__ gumbel,
    int* __restrict__ biOut)
{
    __shared__ float pa[4*1032];        // [h][i][jj], 1032-stride pad  16.5KB
    __shared__ float part[16*256];      // [w|jj][c]                    16KB
    __shared__ float houts[NN*4];       // [k][jj]                      4KB
    __shared__ float redv[4][JT];
    __shared__ int   redi[4][JT];

    int t = threadIdx.x;
    int id = blockIdx.x;
    int xcd = id & 7, k2 = id >> 3;
    int bb = (xcd << 1) | (k2 >> 6);
    int j0 = (k2 & 63) * JT;
    int l = t & 63, w = t >> 6;

    // ---- Phase A: alpha(i=t, j0..j0+3, all h) -> pa ----
    float pr[JT][4];
    if (w*64 <= j0 + JT - 1) {
        float4 as4 = *(const float4*)&a_s[bb*(NN*NH) + t*NH];
        #pragma unroll
        for (int jj = 0; jj < JT; ++jj) {
            int j = j0 + jj;
            float4 ad4 = *(const float4*)&a_d[bb*(NN*NH) + j*NH];
            float4 sv4 = *(const float4*)&sArr[bb*(NN*NH) + j*NH];
            bool valid = (t <= j);
            pr[jj][0] = valid ? expf(lrelu02(as4.x+ad4.x)) * sv4.x : 0.f;
            pr[jj][1] = valid ? expf(lrelu02(as4.y+ad4.y)) * sv4.y : 0.f;
            pr[jj][2] = valid ? expf(lrelu02(as4.z+ad4.z)) * sv4.z : 0.f;
            pr[jj][3] = valid ? expf(lrelu02(as4.w+ad4.w)) * sv4.w : 0.f;
        }
    } else {
        #pragma unroll
        for (int jj = 0; jj < JT; ++jj)
            #pragma unroll
            for (int h = 0; h < 4; ++h) pr[jj][h] = 0.f;
    }
    #pragma unroll
    for (int h = 0; h < 4; ++h)
        *(float4*)&pa[h*1032 + t*4] = make_float4(pr[0][h], pr[1][h], pr[2][h], pr[3][h]);
    __syncthreads();

    // ---- Phase B: aggregate over i <= j0+3 only ----
    int q = l >> 4, c4 = (l & 15) * 4;
    float4 aj[JT];
    #pragma unroll
    for (int jj = 0; jj < JT; ++jj) aj[jj] = make_float4(0.f,0.f,0.f,0.f);
    int lim = j0 + JT - w*64; lim = lim < 0 ? 0 : (lim > 64 ? 64 : lim);
    #pragma unroll 4
    for (int ii = 0; ii < lim; ++ii) {
        int ig = w*64 + ii;
        float4 g4 = *(const float4*)&gfeat[(size_t)bb*(NN*HID) + ig*HID + q*64 + c4];
        float4 pv = *(const float4*)&pa[q*1032 + ig*4];
        aj[0].x = fmaf(pv.x, g4.x, aj[0].x); aj[0].y = fmaf(pv.x, g4.y, aj[0].y);
        aj[0].z = fmaf(pv.x, g4.z, aj[0].z); aj[0].w = fmaf(pv.x, g4.w, aj[0].w);
        aj[1].x = fmaf(pv.y, g4.x, aj[1].x); aj[1].y = fmaf(pv.y, g4.y, aj[1].y);
        aj[1].z = fmaf(pv.y, g4.z, aj[1].z); aj[1].w = fmaf(pv.y, g4.w, aj[1].w);
        aj[2].x = fmaf(pv.z, g4.x, aj[2].x); aj[2].y = fmaf(pv.z, g4.y, aj[2].y);
        aj[2].z = fmaf(pv.z, g4.z, aj[2].z); aj[2].w = fmaf(pv.z, g4.w, aj[2].w);
        aj[3].x = fmaf(pv.w, g4.x, aj[3].x); aj[3].y = fmaf(pv.w, g4.y, aj[3].y);
        aj[3].z = fmaf(pv.w, g4.z, aj[3].z); aj[3].w = fmaf(pv.w, g4.w, aj[3].w);
    }
    #pragma unroll
    for (int jj = 0; jj < JT; ++jj)
        *(float4*)&part[(w*JT + jj)*256 + q*64 + c4] = aj[jj];
    __syncthreads();

    // ---- Phase C: combine waves, +bg, elu -> houts[k][jj] ----
    {
        float bgv = bg[t];
        float hh[JT];
        #pragma unroll
        for (int jj = 0; jj < JT; ++jj) {
            float s = part[(0*JT+jj)*256 + t] + part[(1*JT+jj)*256 + t]
                    + part[(2*JT+jj)*256 + t] + part[(3*JT+jj)*256 + t] + bgv;
            hh[jj] = eluf(s);
        }
        *(float4*)&houts[t*4] = make_float4(hh[0], hh[1], hh[2], hh[3]);
    }
    __syncthreads();

    // ---- Phase D: partial logits over k in [64w, 64w+64) ----
    int cb = l*4;
    float4 lg[JT];
    #pragma unroll
    for (int jj = 0; jj < JT; ++jj) lg[jj] = make_float4(0.f,0.f,0.f,0.f);
    #pragma unroll 2
    for (int kk = 0; kk < 64; ++kk) {
        int k = w*64 + kk;
        float4 hv  = *(const float4*)&houts[k*4];
        float4 wl4 = *(const float4*)&Wl[k*HID + cb];
        lg[0].x = fmaf(hv.x, wl4.x, lg[0].x); lg[0].y = fmaf(hv.x, wl4.y, lg[0].y);
        lg[0].z = fmaf(hv.x, wl4.z, lg[0].z); lg[0].w = fmaf(hv.x, wl4.w, lg[0].w);
        lg[1].x = fmaf(hv.y, wl4.x, lg[1].x); lg[1].y = fmaf(hv.y, wl4.y, lg[1].y);
        lg[1].z = fmaf(hv.y, wl4.z, lg[1].z); lg[1].w = fmaf(hv.y, wl4.w, lg[1].w);
        lg[2].x = fmaf(hv.z, wl4.x, lg[2].x); lg[2].y = fmaf(hv.z, wl4.y, lg[2].y);
        lg[2].z = fmaf(hv.z, wl4.z, lg[2].z); lg[2].w = fmaf(hv.z, wl4.w, lg[2].w);
        lg[3].x = fmaf(hv.w, wl4.x, lg[3].x); lg[3].y = fmaf(hv.w, wl4.y, lg[3].y);
        lg[3].z = fmaf(hv.w, wl4.z, lg[3].z); lg[3].w = fmaf(hv.w, wl4.w, lg[3].w);
    }
    #pragma unroll
    for (int jj = 0; jj < JT; ++jj)
        *(float4*)&part[(w*JT + jj)*256 + cb] = lg[jj];
    __syncthreads();

    // ---- Final: z = logits + bl + gumbel; per-row argmax ----
    float blv = bl[t];
    #pragma unroll
    for (int jj = 0; jj < JT; ++jj) {
        float z = part[(0*JT+jj)*256 + t] + part[(1*JT+jj)*256 + t]
                + part[(2*JT+jj)*256 + t] + part[(3*JT+jj)*256 + t]
                + blv + gumbel[(size_t)bb*(NN*NN) + (j0+jj)*NN + t];
        float bv = z; int bi_ = t;
        #pragma unroll
        for (int off = 1; off < 64; off <<= 1) {
            float ov = __shfl_xor(bv, off);
            int   oi = __shfl_xor(bi_, off);
            if (ov > bv || (ov == bv && oi < bi_)) { bv = ov; bi_ = oi; }
        }
        if (l == 0) { redv[w][jj] = bv; redi[w][jj] = bi_; }
    }
    __syncthreads();
    if (t < JT) {
        float bv = redv[0][t]; int bi_ = redi[0][t];
        #pragma unroll
        for (int ww = 1; ww < 4; ++ww)
            if (redv[ww][t] > bv) { bv = redv[ww][t]; bi_ = redi[ww][t]; }
        biOut[bb*NN + j0 + t] = bi_;
    }
}

// ---------------- K6: zero adj slice + symmetric one-hot scatter ---------------
__global__ __launch_bounds__(256) void k_adj(const int* __restrict__ bi,
    float* __restrict__ adj)
{
    int bb = blockIdx.x, t = threadIdx.x;
    float4* ap = (float4*)(adj + (size_t)bb*(NN*NN));
    float4 z = make_float4(0.f,0.f,0.f,0.f);
    for (int idx = t; idx < NN*NN/4; idx += 256) ap[idx] = z;
    __syncthreads();
    int b = bi[bb*NN + t];
    adj[(size_t)bb*(NN*NN) + t*NN + b] = 1.0f;
    adj[(size_t)bb*(NN*NN) + b*NN + t] = 1.0f;
}

extern "C" void kernel_launch(void* const* d_in, const int* in_sizes, int n_in,
                              void* d_out, int out_size, void* d_ws, size_t ws_size,
                              hipStream_t stream)
{
    const float* x       = (const float*)d_in[0];
    const float* W0      = (const float*)d_in[1];
    const float* b0      = (const float*)d_in[2];
    const float* W1      = (const float*)d_in[3];
    const float* b1      = (const float*)d_in[4];
    const float* W2      = (const float*)d_in[5];
    const float* b2      = (const float*)d_in[6];
    const float* Wg      = (const float*)d_in[7];
    const float* att_src = (const float*)d_in[8];
    const float* att_dst = (const float*)d_in[9];
    const float* bg      = (const float*)d_in[10];
    const float* Wl      = (const float*)d_in[11];
    const float* bl      = (const float*)d_in[12];
    const float* gumbel  = (const float*)d_in[13];

    // ws footprint: 57,344 floats = 229 KB (ws_size appears to be 256 KB —
    // NEVER exceed it; 295 KB failed with silent input corruption).
    float* ws     = (float*)d_ws;
    float* h2     = ws;                    // 4096
    float* a_s    = h2 + 4096;             // 16384
    float* a_d    = a_s + 16384;           // 16384
    float* sArr   = a_d + 16384;           // 16384
    int*   biIdx  = (int*)(sArr + 16384);  // 4096 ints
    // d_out (4MB) triple-duty: h3 -> (in-place) gfeat -> adj
    float* h3g    = (float*)d_out;
    float* adj    = (float*)d_out;

    k_mlp12  <<<NB, 256, 0, stream>>>(x, W0, b0, W1, b1, h2);
    k_h3w    <<<512, 256, 0, stream>>>(h2, W2, b2, h3g);
    k_gfeat  <<<NN, 256, 0, stream>>>(h3g, Wg, att_src, att_dst, a_s, a_d);
    k_prefden<<<256, 256, 0, stream>>>(a_s, a_d, sArr);
    k_gatlog <<<NB*64, 256, 0, stream>>>(h3g, a_s, a_d, sArr, bg, Wl, bl, gumbel, biIdx);
    k_adj    <<<NB, 256, 0, stream>>>(biIdx, adj);
}

// Round 12
// 88.953 us; speedup vs baseline: 7.0327x; 7.0327x over previous
//
#include <hip/hip_runtime.h>
#include <math.h>

#define NB 16      // batch
#define LAT 128
#define HID 256
#define NN 256     // nodes
#define NH 4       // heads
#define JT 4       // dst-tile per gat block

__device__ __forceinline__ float lrelu02(float x){ return x > 0.f ? x : 0.2f*x; }
__device__ __forceinline__ float eluf(float x){ return x > 0.f ? x : expm1f(x); }

// ---------------- K1: h2 = relu(relu(x@W0+b0)@W1+b1)  [16,256] ----------------
__global__ __launch_bounds__(256) void k_mlp12(const float* __restrict__ x,
    const float* __restrict__ W0, const float* __restrict__ b0,
    const float* __restrict__ W1, const float* __restrict__ b1,
    float* __restrict__ h2)
{
    __shared__ float xs[LAT];
    __shared__ float h1s[HID];
    int b = blockIdx.x, t = threadIdx.x;
    if (t < LAT) xs[t] = x[b*LAT + t];
    __syncthreads();
    float acc = b0[t];
    for (int k = 0; k < LAT; ++k) acc = fmaf(xs[k], W0[k*HID + t], acc);
    h1s[t] = fmaxf(acc, 0.f);
    __syncthreads();
    float acc2 = b1[t];
    for (int k = 0; k < HID; ++k) acc2 = fmaf(h1s[k], W1[k*HID + t], acc2);
    h2[b*HID + t] = fmaxf(acc2, 0.f);
}

// ---------------- K2: fused h3 = h2@W2+b2 then gfeat = h3@Wg, a_s/a_d ----------
// 512 threads: k-range split in two halves for 2x memory parallelism on W2.
__global__ __launch_bounds__(512) void k_mlp3g(
    const float* __restrict__ h2, const float* __restrict__ W2,
    const float* __restrict__ b2, const float* __restrict__ Wg,
    const float* __restrict__ att_src, const float* __restrict__ att_dst,
    float* __restrict__ gfeat, float* __restrict__ a_s, float* __restrict__ a_d)
{
    __shared__ float h2T[HID][16];      // [k][b] 16KB
    __shared__ float red[256*17];       // k-half partial sums, padded 17KB
    __shared__ float h3s[NB][HID+1];    // [b][c] 16.4KB
    int t = threadIdx.x;
    int n = blockIdx.x;
    int col = t & 255, kh = t >> 8;
    for (int idx = t; idx < NB*HID; idx += 512) {
        int b = idx & 15, k = idx >> 4;
        h2T[k][b] = h2[b*HID + k];
    }
    __syncthreads();
    float acc[NB];
    #pragma unroll
    for (int b = 0; b < NB; ++b) acc[b] = 0.f;
    const float* w2p = W2 + (size_t)kh*128*65536 + (size_t)n*HID + col;
    for (int k0 = 0; k0 < 128; k0 += 16) {
        float wv[16];
        #pragma unroll
        for (int u = 0; u < 16; ++u) wv[u] = w2p[(size_t)(k0+u)*65536];
        #pragma unroll
        for (int u = 0; u < 16; ++u) {
            const float* hr = &h2T[kh*128 + k0 + u][0];
            #pragma unroll
            for (int b = 0; b < NB; ++b) acc[b] = fmaf(hr[b], wv[u], acc[b]);
        }
    }
    if (kh == 1) {
        #pragma unroll
        for (int b = 0; b < NB; ++b) red[col*17 + b] = acc[b];
    }
    __syncthreads();
    if (kh == 0) {
        float bv = b2[n*HID + col];
        #pragma unroll
        for (int b = 0; b < NB; ++b) h3s[b][col] = acc[b] + red[col*17 + b] + bv;
    }
    __syncthreads();
    // Phase B: 8 waves; wave w handles batches 2w, 2w+1
    int l = t & 63, w = t >> 6, cb = l*4;
    float4 g[2];
    g[0] = make_float4(0.f,0.f,0.f,0.f); g[1] = g[0];
    #pragma unroll 4
    for (int k = 0; k < HID; ++k) {
        float4 wg = *(const float4*)&Wg[k*HID + cb];
        #pragma unroll
        for (int rr = 0; rr < 2; ++rr) {
            float hv = h3s[w*2+rr][k];
            g[rr].x = fmaf(hv, wg.x, g[rr].x);
            g[rr].y = fmaf(hv, wg.y, g[rr].y);
            g[rr].z = fmaf(hv, wg.z, g[rr].z);
            g[rr].w = fmaf(hv, wg.w, g[rr].w);
        }
    }
    float4 s4 = *(const float4*)&att_src[cb];
    float4 d4 = *(const float4*)&att_dst[cb];
    int h = l >> 4;
    #pragma unroll
    for (int rr = 0; rr < 2; ++rr) {
        int b = w*2 + rr;
        *(float4*)&gfeat[b*(NN*HID) + n*HID + cb] = g[rr];
        float ps = g[rr].x*s4.x + g[rr].y*s4.y + g[rr].z*s4.z + g[rr].w*s4.w;
        float pd = g[rr].x*d4.x + g[rr].y*d4.y + g[rr].z*d4.z + g[rr].w*d4.w;
        #pragma unroll
        for (int off = 1; off < 16; off <<= 1) {
            ps += __shfl_xor(ps, off);
            pd += __shfl_xor(pd, off);
        }
        if ((l & 15) == 0) {
            a_s[b*(NN*NH) + n*NH + h] = ps;
            a_d[b*(NN*NH) + n*NH + h] = pd;
        }
    }
}

// ---------------- K3: per (b,h,j): S_j = exp(-m_j)/den_j  (single buffer) ------
// grid 256 = (b, h, jchunk); 4 lanes cooperate per j.
__global__ __launch_bounds__(256) void k_prefden(const float* __restrict__ a_s,
    const float* __restrict__ a_d, float* __restrict__ sArr)
{
    __shared__ float as_sh[NN];
    int id = blockIdx.x;
    int b = id >> 4, h = (id >> 2) & 3, jc = id & 3;
    int t = threadIdx.x;
    as_sh[t] = a_s[b*(NN*NH) + t*NH + h];
    __syncthreads();
    int jl = t >> 2, r = t & 3;
    int j = jc*64 + jl;
    float ad = a_d[b*(NN*NH) + j*NH + h];
    // pass 1: max over i <= j (4-lane split)
    float lm = -INFINITY;
    for (int i = r; i <= j; i += 4) lm = fmaxf(lm, as_sh[i]);
    lm = fmaxf(lm, __shfl_xor(lm, 1));
    lm = fmaxf(lm, __shfl_xor(lm, 2));
    float m = lrelu02(lm + ad);
    // pass 2: denom of exp(e - m)
    float s = 0.f;
    for (int i = r; i <= j; i += 4) s += expf(lrelu02(as_sh[i] + ad) - m);
    s += __shfl_xor(s, 1);
    s += __shfl_xor(s, 2);
    if (r == 0) {
        // alpha_ij = exp(e_ij) * S_j ; scores are O(0.3) so exp() is safe
        sArr[b*(NN*NH) + j*NH + h] = expf(-m) / s;
    }
}

// ---------------- K4: fused alpha + aggregate + elu + logits + argmax ----------
__global__ __launch_bounds__(256) void k_gatlog(
    const float* __restrict__ gfeat, const float* __restrict__ a_s,
    const float* __restrict__ a_d, const float* __restrict__ sArr,
    const float* __restrict__ bg, const float* __restrict__ Wl,
    const float* __restrict__ bl, const float* __restrict__ gumbel,
    int* __restrict__ biOut)
{
    __shared__ float pa[4*1032];        // [h][i][jj], 1032-stride pad  16.5KB
    __shared__ float part[16*256];      // [w|jj][c]                    16KB
    __shared__ float houts[NN*4];       // [k][jj]                      4KB
    __shared__ float redv[4][JT];
    __shared__ int   redi[4][JT];

    int t = threadIdx.x;
    // XCD swizzle: block i lands on XCD i%8; give each XCD 2 whole batches.
    int id = blockIdx.x;
    int xcd = id & 7, k2 = id >> 3;
    int bb = (xcd << 1) | (k2 >> 6);
    int j0 = (k2 & 63) * JT;
    int l = t & 63, w = t >> 6;

    // ---- Phase A: alpha(i=t, j0..j0+3, all h) -> pa ----
    float pr[JT][4];
    if (w*64 <= j0 + JT - 1) {
        float4 as4 = *(const float4*)&a_s[bb*(NN*NH) + t*NH];
        #pragma unroll
        for (int jj = 0; jj < JT; ++jj) {
            int j = j0 + jj;
            float4 ad4 = *(const float4*)&a_d[bb*(NN*NH) + j*NH];
            float4 sv4 = *(const float4*)&sArr[bb*(NN*NH) + j*NH];
            bool valid = (t <= j);
            pr[jj][0] = valid ? expf(lrelu02(as4.x+ad4.x)) * sv4.x : 0.f;
            pr[jj][1] = valid ? expf(lrelu02(as4.y+ad4.y)) * sv4.y : 0.f;
            pr[jj][2] = valid ? expf(lrelu02(as4.z+ad4.z)) * sv4.z : 0.f;
            pr[jj][3] = valid ? expf(lrelu02(as4.w+ad4.w)) * sv4.w : 0.f;
        }
    } else {
        #pragma unroll
        for (int jj = 0; jj < JT; ++jj)
            #pragma unroll
            for (int h = 0; h < 4; ++h) pr[jj][h] = 0.f;
    }
    #pragma unroll
    for (int h = 0; h < 4; ++h)
        *(float4*)&pa[h*1032 + t*4] = make_float4(pr[0][h], pr[1][h], pr[2][h], pr[3][h]);
    __syncthreads();

    // ---- Phase B: aggregate over i <= j0+3 only (alpha is 0 above diagonal) ----
    int q = l >> 4, c4 = (l & 15) * 4;        // channel q*64+c4
    float4 aj[JT];
    #pragma unroll
    for (int jj = 0; jj < JT; ++jj) aj[jj] = make_float4(0.f,0.f,0.f,0.f);
    const float* gb = gfeat + bb*(NN*HID);
    int lim = j0 + JT - w*64; lim = lim < 0 ? 0 : (lim > 64 ? 64 : lim);
    #pragma unroll 4
    for (int ii = 0; ii < lim; ++ii) {
        int ig = w*64 + ii;
        float4 g4 = *(const float4*)&gb[ig*HID + q*64 + c4];
        float4 pv = *(const float4*)&pa[q*1032 + ig*4];
        aj[0].x = fmaf(pv.x, g4.x, aj[0].x); aj[0].y = fmaf(pv.x, g4.y, aj[0].y);
        aj[0].z = fmaf(pv.x, g4.z, aj[0].z); aj[0].w = fmaf(pv.x, g4.w, aj[0].w);
        aj[1].x = fmaf(pv.y, g4.x, aj[1].x); aj[1].y = fmaf(pv.y, g4.y, aj[1].y);
        aj[1].z = fmaf(pv.y, g4.z, aj[1].z); aj[1].w = fmaf(pv.y, g4.w, aj[1].w);
        aj[2].x = fmaf(pv.z, g4.x, aj[2].x); aj[2].y = fmaf(pv.z, g4.y, aj[2].y);
        aj[2].z = fmaf(pv.z, g4.z, aj[2].z); aj[2].w = fmaf(pv.z, g4.w, aj[2].w);
        aj[3].x = fmaf(pv.w, g4.x, aj[3].x); aj[3].y = fmaf(pv.w, g4.y, aj[3].y);
        aj[3].z = fmaf(pv.w, g4.z, aj[3].z); aj[3].w = fmaf(pv.w, g4.w, aj[3].w);
    }
    #pragma unroll
    for (int jj = 0; jj < JT; ++jj)
        *(float4*)&part[(w*JT + jj)*256 + q*64 + c4] = aj[jj];
    __syncthreads();

    // ---- Phase C: combine waves, +bg, elu -> houts[k][jj] ----
    {
        float bgv = bg[t];
        float hh[JT];
        #pragma unroll
        for (int jj = 0; jj < JT; ++jj) {
            float s = part[(0*JT+jj)*256 + t] + part[(1*JT+jj)*256 + t]
                    + part[(2*JT+jj)*256 + t] + part[(3*JT+jj)*256 + t] + bgv;
            hh[jj] = eluf(s);
        }
        *(float4*)&houts[t*4] = make_float4(hh[0], hh[1], hh[2], hh[3]);
    }
    __syncthreads();

    // ---- Phase D: partial logits over k in [64w, 64w+64) ----
    int cb = l*4;
    float4 lg[JT];
    #pragma unroll
    for (int jj = 0; jj < JT; ++jj) lg[jj] = make_float4(0.f,0.f,0.f,0.f);
    #pragma unroll 2
    for (int kk = 0; kk < 64; ++kk) {
        int k = w*64 + kk;
        float4 hv  = *(const float4*)&houts[k*4];
        float4 wl4 = *(const float4*)&Wl[k*HID + cb];
        lg[0].x = fmaf(hv.x, wl4.x, lg[0].x); lg[0].y = fmaf(hv.x, wl4.y, lg[0].y);
        lg[0].z = fmaf(hv.x, wl4.z, lg[0].z); lg[0].w = fmaf(hv.x, wl4.w, lg[0].w);
        lg[1].x = fmaf(hv.y, wl4.x, lg[1].x); lg[1].y = fmaf(hv.y, wl4.y, lg[1].y);
        lg[1].z = fmaf(hv.y, wl4.z, lg[1].z); lg[1].w = fmaf(hv.y, wl4.w, lg[1].w);
        lg[2].x = fmaf(hv.z, wl4.x, lg[2].x); lg[2].y = fmaf(hv.z, wl4.y, lg[2].y);
        lg[2].z = fmaf(hv.z, wl4.z, lg[2].z); lg[2].w = fmaf(hv.z, wl4.w, lg[2].w);
        lg[3].x = fmaf(hv.w, wl4.x, lg[3].x); lg[3].y = fmaf(hv.w, wl4.y, lg[3].y);
        lg[3].z = fmaf(hv.w, wl4.z, lg[3].z); lg[3].w = fmaf(hv.w, wl4.w, lg[3].w);
    }
    #pragma unroll
    for (int jj = 0; jj < JT; ++jj)
        *(float4*)&part[(w*JT + jj)*256 + cb] = lg[jj];
    __syncthreads();

    // ---- Final: z = logits + bl + gumbel; per-row argmax ----
    float blv = bl[t];
    #pragma unroll
    for (int jj = 0; jj < JT; ++jj) {
        float z = part[(0*JT+jj)*256 + t] + part[(1*JT+jj)*256 + t]
                + part[(2*JT+jj)*256 + t] + part[(3*JT+jj)*256 + t]
                + blv + gumbel[bb*(NN*NN) + (j0+jj)*NN + t];
        float bv = z; int bi_ = t;
        #pragma unroll
        for (int off = 1; off < 64; off <<= 1) {
            float ov = __shfl_xor(bv, off);
            int   oi = __shfl_xor(bi_, off);
            if (ov > bv || (ov == bv && oi < bi_)) { bv = ov; bi_ = oi; }
        }
        if (l == 0) { redv[w][jj] = bv; redi[w][jj] = bi_; }
    }
    __syncthreads();
    if (t < JT) {
        float bv = redv[0][t]; int bi_ = redi[0][t];
        #pragma unroll
        for (int ww = 1; ww < 4; ++ww)
            if (redv[ww][t] > bv) { bv = redv[ww][t]; bi_ = redi[ww][t]; }
        biOut[bb*NN + j0 + t] = bi_;
    }
}

// ---------------- K5: zero adj slice + symmetric one-hot scatter ---------------
__global__ __launch_bounds__(256) void k_adj(const int* __restrict__ bi,
    float* __restrict__ adj)
{
    int bb = blockIdx.x, t = threadIdx.x;
    float4* ap = (float4*)(adj + (size_t)bb*(NN*NN));
    float4 z = make_float4(0.f,0.f,0.f,0.f);
    for (int idx = t; idx < NN*NN/4; idx += 256) ap[idx] = z;
    __syncthreads();
    int b = bi[bb*NN + t];
    adj[(size_t)bb*(NN*NN) + t*NN + b] = 1.0f;
    adj[(size_t)bb*(NN*NN) + b*NN + t] = 1.0f;
}

extern "C" void kernel_launch(void* const* d_in, const int* in_sizes, int n_in,
                              void* d_out, int out_size, void* d_ws, size_t ws_size,
                              hipStream_t stream)
{
    const float* x       = (const float*)d_in[0];
    const float* W0      = (const float*)d_in[1];
    const float* b0      = (const float*)d_in[2];
    const float* W1      = (const float*)d_in[3];
    const float* b1      = (const float*)d_in[4];
    const float* W2      = (const float*)d_in[5];
    const float* b2      = (const float*)d_in[6];
    const float* Wg      = (const float*)d_in[7];
    const float* att_src = (const float*)d_in[8];
    const float* att_dst = (const float*)d_in[9];
    const float* bg      = (const float*)d_in[10];
    const float* Wl      = (const float*)d_in[11];
    const float* bl      = (const float*)d_in[12];
    const float* gumbel  = (const float*)d_in[13];

    // ws footprint: 57,344 floats = 229 KB (same as the passing Round-2 layout;
    // ws_size appears to be 256 KB — NEVER exceed it).
    float* ws     = (float*)d_ws;
    float* h2     = ws;                    // 4096
    float* a_s    = h2 + 4096;             // 16384
    float* a_d    = a_s + 16384;           // 16384
    float* sArr   = a_d + 16384;           // 16384
    int*   biIdx  = (int*)(sArr + 16384);  // 4096 ints
    float* gfeat  = (float*)d_out;         // d_out doubles as gfeat scratch (4MB)
    float* adj    = (float*)d_out;

    k_mlp12  <<<NB, 256, 0, stream>>>(x, W0, b0, W1, b1, h2);
    k_mlp3g  <<<NN, 512, 0, stream>>>(h2, W2, b2, Wg, att_src, att_dst, gfeat, a_s, a_d);
    k_prefden<<<256, 256, 0, stream>>>(a_s, a_d, sArr);
    k_gatlog <<<NB*64, 256, 0, stream>>>(gfeat, a_s, a_d, sArr, bg, Wl, bl, gumbel, biIdx);
    k_adj    <<<NB, 256, 0, stream>>>(biIdx, adj);
}